// Round 1
// baseline (567.594 us; speedup 1.0000x reference)
//
#include <hip/hip_runtime.h>
#include <math.h>

#define BB 32
#define HH 12
#define CC 512
#define DD 768
#define MM 8
#define NER 6
#define NCLS 97
#define KTOT 1542   // 2*D + NER
#define OFFS 1
#define KCH 193     // K-chunk for head/tail GEMM (8*193 = 1544 >= 1542)

// ---------------------------------------------------------------------------
// ws layout (float offsets):
//   raw     [B*C]      @ 0        (zeroed)   un-normalized ht_att
//   Sb      [B]        @ 16384               sum_c raw
//   rs_part [B*16*D]   @ 16416               partial rs over c-chunks
//   rs      [B*D]      @ 409632
//   hs      [B*D]      @ 434208              logsumexp entity embedding (e=0)
//   accf    [2*B*D]    @ 458784  (zeroed)    pre-tanh head/tail accumulators
//   fbuf    [2*B*D]    @ 507936              tanh'd hs_f (e=0) / ts_f (e=1)
// total 557088 floats = 2.23 MB
// ---------------------------------------------------------------------------

// ht_att accumulation: grid (B,H), block 512 (one thread per c).
// contrib per h: (mean_m a0)(mean_m a1)/H  -> factor 1/(M*M*H)
__global__ void k_att(const float* __restrict__ att, const int* __restrict__ epos,
                      float* __restrict__ raw) {
    int b = blockIdx.x, h = blockIdx.y;
    __shared__ int pos[16];
    if (threadIdx.x < 16) pos[threadIdx.x] = epos[b * 16 + threadIdx.x] + OFFS;
    __syncthreads();
    int c = threadIdx.x;
    const float* base = att + ((size_t)(b * HH + h)) * CC * CC;
    float a0 = 0.f, a1 = 0.f;
#pragma unroll
    for (int m = 0; m < MM; m++) {
        a0 += base[(size_t)pos[m] * CC + c];
        a1 += base[(size_t)pos[MM + m] * CC + c];
    }
    atomicAdd(&raw[b * CC + c], a0 * a1 * (1.0f / (MM * MM * HH)));
}

// rs partials: grid (B,16), block 192; thread owns 4 d's (float4), loops 32 c.
// blocks with cc==0 also reduce S_b = sum_c raw[b,c].
__global__ void k_rs_part(const float* __restrict__ seq, const float* __restrict__ raw,
                          float* __restrict__ rs_part, float* __restrict__ Sb) {
    int b = blockIdx.x, cc = blockIdx.y, t = threadIdx.x;
    float4 acc = {0.f, 0.f, 0.f, 0.f};
    const float* rw = raw + b * CC + cc * 32;
    const float* sp = seq + ((size_t)b * CC + cc * 32) * DD + t * 4;
    for (int ci = 0; ci < 32; ci++) {
        float w = rw[ci];
        float4 v = *(const float4*)(sp + (size_t)ci * DD);
        acc.x += v.x * w; acc.y += v.y * w; acc.z += v.z * w; acc.w += v.w * w;
    }
    *(float4*)&rs_part[((size_t)(b * 16 + cc)) * DD + t * 4] = acc;
    if (cc == 0) {
        __shared__ float sb[192];
        float s = 0.f;
        for (int c = t; c < CC; c += 192) s += raw[b * CC + c];
        sb[t] = s;
        __syncthreads();
        if (t == 0) {
            float tot = 0.f;
            for (int i = 0; i < 192; i++) tot += sb[i];
            Sb[b] = tot;
        }
    }
}

// finalize rs (divide by S_b + 1e-5) and compute hs = logsumexp over M rows.
// grid B, block 192 (float4 per thread).
__global__ void k_rs_hs(const float* __restrict__ seq, const int* __restrict__ epos,
                        const float* __restrict__ rs_part, const float* __restrict__ Sb,
                        float* __restrict__ rs, float* __restrict__ hs) {
    int b = blockIdx.x, t = threadIdx.x;
    __shared__ int pos[MM];
    if (t < MM) pos[t] = epos[b * 16 + t] + OFFS;   // e = 0 rows only
    __syncthreads();
    float4 acc = {0.f, 0.f, 0.f, 0.f};
    for (int cc = 0; cc < 16; cc++) {
        float4 p = *(const float4*)&rs_part[((size_t)(b * 16 + cc)) * DD + t * 4];
        acc.x += p.x; acc.y += p.y; acc.z += p.z; acc.w += p.w;
    }
    float inv = 1.0f / (Sb[b] + 1e-5f);
    float4 r = {acc.x * inv, acc.y * inv, acc.z * inv, acc.w * inv};
    *(float4*)&rs[b * DD + t * 4] = r;

    float xs0[MM], xs1[MM], xs2[MM], xs3[MM];
#pragma unroll
    for (int m = 0; m < MM; m++) {
        float4 v = *(const float4*)&seq[((size_t)b * CC + pos[m]) * DD + t * 4];
        xs0[m] = v.x; xs1[m] = v.y; xs2[m] = v.z; xs3[m] = v.w;
    }
    float o[4];
    float* xs[4] = {xs0, xs1, xs2, xs3};
#pragma unroll
    for (int comp = 0; comp < 4; comp++) {
        float mx = xs[comp][0];
#pragma unroll
        for (int m = 1; m < MM; m++) mx = fmaxf(mx, xs[comp][m]);
        float se = 0.f;
#pragma unroll
        for (int m = 0; m < MM; m++) se += expf(xs[comp][m] - mx);
        o[comp] = logf(se) + mx;
    }
    float4 hv = {o[0], o[1], o[2], o[3]};
    *(float4*)&hs[b * DD + t * 4] = hv;
}

// head/tail GEMM partials: grid (kt=8, jt=12, e=2), block 256.
// Stages A[b, k-chunk] in LDS (stride 193 -> conflict-free across b lanes).
// Each thread owns (b, 8 consecutive j), atomicAdd partial dot into accf.
__global__ void k_headtail(const float* __restrict__ hs, const float* __restrict__ rs,
                           const float* __restrict__ ner, const float* __restrict__ Wh,
                           const float* __restrict__ Wt, float* __restrict__ accf) {
    int kt = blockIdx.x, jt = blockIdx.y, e = blockIdx.z;
    int kstart = kt * KCH;
    int klen = min(KCH, KTOT - kstart);
    __shared__ float A[32][KCH];
    for (int i = threadIdx.x; i < 32 * KCH; i += 256) {
        int bb = i / KCH, kk = i - bb * KCH;
        int k = kstart + kk;
        float v = 0.f;
        if (k < KTOT) {
            if (k < DD) v = hs[bb * DD + k];
            else if (k < 2 * DD) v = rs[bb * DD + (k - DD)];
            else v = ner[(bb * 2 + e) * NER + (k - 2 * DD)];
        }
        A[bb][kk] = v;
    }
    __syncthreads();
    int b = threadIdx.x & 31, jq = threadIdx.x >> 5;
    int j0 = jt * 64 + jq * 8;
    const float* W = e ? Wt : Wh;
    const float* Wb = W + (size_t)j0 * KTOT + kstart;
    float acc[8] = {0.f, 0.f, 0.f, 0.f, 0.f, 0.f, 0.f, 0.f};
#pragma unroll 4
    for (int kk = 0; kk < klen; kk++) {
        float a = A[b][kk];
#pragma unroll
        for (int jj = 0; jj < 8; jj++) acc[jj] += a * Wb[(size_t)jj * KTOT + kk];
    }
    float* outp = accf + ((size_t)(e * 32 + b)) * DD + j0;
#pragma unroll
    for (int jj = 0; jj < 8; jj++) atomicAdd(&outp[jj], acc[jj]);
}

// bias + tanh: 2*B*D = 49152 elements.
__global__ void k_tanh(const float* __restrict__ accf, const float* __restrict__ bh,
                       const float* __restrict__ bt, float* __restrict__ fbuf) {
    int x = blockIdx.x * 256 + threadIdx.x;
    int e = x / (BB * DD);
    int r = x - e * (BB * DD);
    int j = r % DD;
    float bias = e ? bt[j] : bh[j];
    fbuf[x] = tanhf(accf[x] + bias);
}

// bilinear + final matmul: grid NCLS, block 256 (32 b x 8 k-groups).
// logits[b,n] = sum_{f,i,j} hsf[b,f*8+i] * tsf[b,f*8+j] * W[n, f*64+i*8+j] + bias
__global__ void k_bil(const float* __restrict__ fbuf, const float* __restrict__ Wb,
                      const float* __restrict__ bbil, float* __restrict__ out) {
    int n = blockIdx.x;
    int g = threadIdx.x & 7, b = threadIdx.x >> 3;
    const float* hsf = fbuf + b * DD;
    const float* tsf = fbuf + (32 + b) * DD;
    const float* W = Wb + (size_t)n * (DD * 8);
    float acc = 0.f;
    for (int t = 0; t < 12; t++) {
        int f = g + 8 * t;
        float4 h0 = *(const float4*)&hsf[f * 8];
        float4 h1 = *(const float4*)&hsf[f * 8 + 4];
        float4 t0 = *(const float4*)&tsf[f * 8];
        float4 t1 = *(const float4*)&tsf[f * 8 + 4];
        float hv[8] = {h0.x, h0.y, h0.z, h0.w, h1.x, h1.y, h1.z, h1.w};
        float tv[8] = {t0.x, t0.y, t0.z, t0.w, t1.x, t1.y, t1.z, t1.w};
        const float* wf = W + f * 64;
#pragma unroll
        for (int i = 0; i < 8; i++) {
            float4 w0 = *(const float4*)&wf[i * 8];
            float4 w1 = *(const float4*)&wf[i * 8 + 4];
            float dot = tv[0] * w0.x + tv[1] * w0.y + tv[2] * w0.z + tv[3] * w0.w
                      + tv[4] * w1.x + tv[5] * w1.y + tv[6] * w1.z + tv[7] * w1.w;
            acc += hv[i] * dot;
        }
    }
    __shared__ float part[32 * 9];
    part[b * 9 + g] = acc;
    __syncthreads();
    if (g == 0) {
        float s = 0.f;
#pragma unroll
        for (int i = 0; i < 8; i++) s += part[b * 9 + i];
        out[b * NCLS + n] = s + bbil[n];
    }
}

extern "C" void kernel_launch(void* const* d_in, const int* in_sizes, int n_in,
                              void* d_out, int out_size, void* d_ws, size_t ws_size,
                              hipStream_t stream) {
    const float* seq  = (const float*)d_in[0];
    const float* att  = (const float*)d_in[1];
    const float* ner  = (const float*)d_in[2];
    const float* Wh   = (const float*)d_in[3];
    const float* bh   = (const float*)d_in[4];
    const float* Wt   = (const float*)d_in[5];
    const float* bt   = (const float*)d_in[6];
    const float* Wbil = (const float*)d_in[7];
    const float* bbil = (const float*)d_in[8];
    const int*   epos = (const int*)d_in[9];
    float* out = (float*)d_out;
    float* ws = (float*)d_ws;

    float* raw     = ws;
    float* Sb      = ws + 16384;
    float* rs_part = ws + 16416;
    float* rs      = ws + 409632;
    float* hs      = ws + 434208;
    float* accf    = ws + 458784;
    float* fbuf    = ws + 507936;

    hipMemsetAsync(raw, 0, (size_t)16384 * 4, stream);
    hipMemsetAsync(accf, 0, (size_t)49152 * 4, stream);

    k_att<<<dim3(BB, HH), 512, 0, stream>>>(att, epos, raw);
    k_rs_part<<<dim3(BB, 16), 192, 0, stream>>>(seq, raw, rs_part, Sb);
    k_rs_hs<<<BB, 192, 0, stream>>>(seq, epos, rs_part, Sb, rs, hs);
    k_headtail<<<dim3(8, 12, 2), 256, 0, stream>>>(hs, rs, ner, Wh, Wt, accf);
    k_tanh<<<192, 256, 0, stream>>>(accf, bh, bt, fbuf);
    k_bil<<<NCLS, 256, 0, stream>>>(fbuf, Wbil, bbil, out);
}